// Round 1
// baseline (314.122 us; speedup 1.0000x reference)
//
#include <hip/hip_runtime.h>

// ---------- constants ----------
#define B_   16
#define C_   256
#define OC_  256
#define H_   64
#define W_   64
#define NE_  3

typedef __attribute__((ext_vector_type(8))) __bf16 bf16x8;
typedef __attribute__((ext_vector_type(4))) float  f32x4;

__device__ __forceinline__ short f2bf(float f) {
    unsigned u = __float_as_uint(f);
    u += 0x7fffu + ((u >> 16) & 1u);
    return (short)(u >> 16);
}

__device__ __forceinline__ void gll16(const void* g, void* l) {
    __builtin_amdgcn_global_load_lds(
        (const __attribute__((address_space(1))) unsigned int*)g,
        (__attribute__((address_space(3))) unsigned int*)l,
        16, 0, 0);
}

// ---------- kernel 1: x (fp32, NCHW) -> x_t (bf16, [b][y][x][c]) + pooling partials ----------
// pp[b][y][c][sj] = sum over 16 x of row y, x-block sj
__global__ __launch_bounds__(256) void k_transpose_pool(
        const float* __restrict__ x, short* __restrict__ xt, float* __restrict__ pp) {
    int y = blockIdx.x;   // 0..63
    int b = blockIdx.y;   // 0..15
    int t = threadIdx.x;  // 0..255
    __shared__ float tile[64 * 65];

    for (int cc = 0; cc < 4; ++cc) {
        int cbase = cc * 64;
        // load 64 c x 64 x (coalesced rows)
        for (int q = 0; q < 16; ++q) {
            int c_l = q * 4 + (t >> 6);
            int xx  = t & 63;
            tile[c_l * 65 + xx] =
                x[(((size_t)b * C_ + cbase + c_l) * H_ + y) * W_ + xx];
        }
        __syncthreads();
        // pooling partials: per (c, sj) sum 16 x
        {
            int c_l = t >> 2, sj = t & 3;
            float s = 0.f;
            #pragma unroll
            for (int u = 0; u < 16; ++u) s += tile[c_l * 65 + sj * 16 + u];
            pp[(((size_t)b * H_ + y) * C_ + cbase + c_l) * 4 + sj] = s;
        }
        // transposed bf16 write (coalesced in c)
        for (int q = 0; q < 16; ++q) {
            int c_l = t & 63;
            int xx  = q * 4 + (t >> 6);
            xt[(((size_t)b * H_ + y) * W_ + xx) * C_ + cbase + c_l] =
                f2bf(tile[c_l * 65 + xx]);
        }
        __syncthreads();
    }
}

// ---------- kernel 2: routing head -> r[b][k][c] ----------
__global__ __launch_bounds__(256) void k_route(
        const float* __restrict__ pp, const float* __restrict__ rconv_w,
        const float* __restrict__ rconv_b, const float* __restrict__ fc_w,
        const float* __restrict__ fc_b, float* __restrict__ r_buf) {
    int b = blockIdx.x;
    int t = threadIdx.x;
    __shared__ float pooled[256 * 16];  // [c][si*4+sj]
    __shared__ float y1[256];           // [rcc*16 + ss]

    {   // finish adaptive avg pool: sum 16 rows per si
        int c = t;
        #pragma unroll
        for (int si = 0; si < 4; ++si)
            #pragma unroll
            for (int sj = 0; sj < 4; ++sj) {
                float s = 0.f;
                #pragma unroll 4
                for (int u = 0; u < 16; ++u)
                    s += pp[(((size_t)b * H_ + si * 16 + u) * C_ + c) * 4 + sj];
                pooled[c * 16 + si * 4 + sj] = s * (1.0f / 256.0f);
            }
    }
    __syncthreads();
    {   // 1x1 conv (rc=16) + relu, laid out to match reshape order rcc*16+ss
        int rcc = t >> 4, ss = t & 15;
        float acc = rconv_b[rcc];
        #pragma unroll 8
        for (int c = 0; c < 256; ++c)
            acc += pooled[c * 16 + ss] * rconv_w[rcc * 256 + c];
        y1[rcc * 16 + ss] = fmaxf(acc, 0.f);
    }
    __syncthreads();
    // FC (768x256) + relu + sigmoid
    for (int e0 = 0; e0 < 768; e0 += 256) {
        int e = e0 + t;
        float acc = fc_b[e];
        #pragma unroll 8
        for (int q = 0; q < 256; ++q)
            acc += y1[q] * fc_w[(size_t)e * 256 + q];
        acc = fmaxf(acc, 0.f);
        r_buf[(size_t)b * 768 + e] = 1.f / (1.f + __expf(-acc));
    }
}

// ---------- kernel 3: combine experts -> wcomb[b][o][tap][c] (bf16) ----------
__global__ __launch_bounds__(256) void k_combine(
        const float* __restrict__ E, const float* __restrict__ r_buf,
        short* __restrict__ wcomb) {
    int o = blockIdx.x;
    int b = blockIdx.y;
    int c = threadIdx.x;
    float r0 = r_buf[(size_t)b * 768 + c];
    float r1 = r_buf[(size_t)b * 768 + 256 + c];
    float r2 = r_buf[(size_t)b * 768 + 512 + c];
    const float* e0 = E + (((size_t)0 * OC_ + o) * C_ + c) * 9;
    const float* e1 = E + (((size_t)1 * OC_ + o) * C_ + c) * 9;
    const float* e2 = E + (((size_t)2 * OC_ + o) * C_ + c) * 9;
    short* wo = wcomb + (((size_t)b * OC_ + o) * 9) * C_ + c;
    #pragma unroll
    for (int tap = 0; tap < 9; ++tap)
        wo[(size_t)tap * C_] = f2bf(r0 * e0[tap] + r1 * e1[tap] + r2 * e2[tap]);
}

// ---------- kernel 4: implicit-GEMM conv, M=128 o-channels x N=128 positions ----------
// Grid: (32 y-pairs, 2 o-blocks, 16 samples). K = tap-major (9) x 8 chunks of 32 ch.
__global__ __launch_bounds__(256) void k_conv(
        const short* __restrict__ xt, const short* __restrict__ wcomb,
        float* __restrict__ out, const short* __restrict__ zbuf) {
    int yb     = blockIdx.x;        // 0..31 -> rows y0, y0+1
    int o_base = blockIdx.y * 128;  // 0 or 128
    int b      = blockIdx.z;
    int t    = threadIdx.x;
    int lane = t & 63, w = t >> 6;
    int quad = lane >> 4, l15 = lane & 15;
    int y0 = yb * 2;

    __shared__ __align__(16) short aT[128 * 32];  // weights [o_local][ch]
    __shared__ __align__(16) short bT[128 * 32];  // x       [p_local][ch]

    f32x4 acc[4][4];
    #pragma unroll
    for (int i = 0; i < 4; ++i)
        #pragma unroll
        for (int j = 0; j < 4; ++j) acc[i][j] = {0.f, 0.f, 0.f, 0.f};

    int m_base = (w & 1) * 64;   // o-dim within 128
    int n_base = (w >> 1) * 64;  // position-dim within 128

    for (int kc = 0; kc < 72; ++kc) {
        int tap = kc >> 3, cc = kc & 7;
        int ti = tap / 3, tj = tap % 3;
        __syncthreads();
        // stage A: weights, 512 groups of 8 bf16
        #pragma unroll
        for (int q = 0; q < 2; ++q) {
            int gb = (w * 2 + q) * 64;
            int g  = gb + lane;
            int o_l = g >> 2, ch8 = g & 3;
            const short* gp = wcomb +
                ((((size_t)b * OC_ + o_base + o_l) * 9 + tap) * C_ + cc * 32 + ch8 * 8);
            gll16(gp, &aT[gb * 8]);
        }
        // stage B: shifted x window, OOB -> zeros
        #pragma unroll
        for (int q = 0; q < 2; ++q) {
            int gb = (w * 2 + q) * 64;
            int g  = gb + lane;
            int p_l = g >> 2, ch8 = g & 3;
            int row = p_l >> 6, xx = p_l & 63;
            int yy = y0 + row + ti - 1;
            int xc = xx + tj - 1;
            bool valid = ((unsigned)yy < (unsigned)H_) && ((unsigned)xc < (unsigned)W_);
            const short* gp = valid
                ? xt + (((size_t)b * H_ + yy) * W_ + xc) * C_ + cc * 32 + ch8 * 8
                : zbuf;
            gll16(gp, &bT[gb * 8]);
        }
        __syncthreads();

        bf16x8 af[4], bfv[4];
        #pragma unroll
        for (int mb = 0; mb < 4; ++mb)
            af[mb] = *(const bf16x8*)&aT[(m_base + mb * 16 + l15) * 32 + quad * 8];
        #pragma unroll
        for (int nb = 0; nb < 4; ++nb)
            bfv[nb] = *(const bf16x8*)&bT[(n_base + nb * 16 + l15) * 32 + quad * 8];
        #pragma unroll
        for (int mb = 0; mb < 4; ++mb)
            #pragma unroll
            for (int nb = 0; nb < 4; ++nb)
                acc[mb][nb] = __builtin_amdgcn_mfma_f32_16x16x32_bf16(
                    af[mb], bfv[nb], acc[mb][nb], 0, 0, 0);
    }

    // epilogue: D[m=o][n=p]; n = lane&15 -> consecutive x => coalesced stores
    #pragma unroll
    for (int mb = 0; mb < 4; ++mb) {
        #pragma unroll
        for (int nb = 0; nb < 4; ++nb) {
            int p  = n_base + nb * 16 + l15;
            int yy = y0 + (p >> 6);
            int xx = p & 63;
            #pragma unroll
            for (int rg = 0; rg < 4; ++rg) {
                int o = o_base + m_base + mb * 16 + quad * 4 + rg;
                out[(((size_t)b * OC_ + o) * H_ + yy) * W_ + xx] = acc[mb][nb][rg];
            }
        }
    }
}

// ---------- launcher ----------
extern "C" void kernel_launch(void* const* d_in, const int* in_sizes, int n_in,
                              void* d_out, int out_size, void* d_ws, size_t ws_size,
                              hipStream_t stream) {
    const float* x       = (const float*)d_in[0];
    const float* E       = (const float*)d_in[1];
    const float* rconv_w = (const float*)d_in[2];
    const float* rconv_b = (const float*)d_in[3];
    const float* fc_w    = (const float*)d_in[4];
    const float* fc_b    = (const float*)d_in[5];
    float* out = (float*)d_out;

    char* ws = (char*)d_ws;
    short* xt    = (short*)(ws);                       // 16*64*64*256 bf16 = 32 MiB
    short* wcomb = (short*)(ws + 33554432);            // 16*256*9*256 bf16 = 18 MiB
    float* pp    = (float*)(ws + 52428800);            // 16*64*256*4 f32 = 4 MiB
    float* rbuf  = (float*)(ws + 56623104);            // 16*768 f32
    short* zbuf  = (short*)(ws + 56672256);            // 256 B zeros

    hipMemsetAsync(zbuf, 0, 256, stream);

    k_transpose_pool<<<dim3(64, 16), 256, 0, stream>>>(x, xt, pp);
    k_route<<<dim3(16), 256, 0, stream>>>(pp, rconv_w, rconv_b, fc_w, fc_b, rbuf);
    k_combine<<<dim3(256, 16), 256, 0, stream>>>(E, rbuf, wcomb);
    k_conv<<<dim3(32, 2, 16), 256, 0, stream>>>(xt, wcomb, out, zbuf);
}

// Round 2
// 261.823 us; speedup vs baseline: 1.1997x; 1.1997x over previous
//
#include <hip/hip_runtime.h>

// ---------- constants ----------
#define B_   16
#define C_   256
#define OC_  256
#define H_   64
#define W_   64
#define NE_  3

typedef __attribute__((ext_vector_type(8))) __bf16 bf16x8;
typedef __attribute__((ext_vector_type(4))) float  f32x4;

__device__ __forceinline__ short f2bf(float f) {
    unsigned u = __float_as_uint(f);
    u += 0x7fffu + ((u >> 16) & 1u);
    return (short)(u >> 16);
}

__device__ __forceinline__ void gll16(const void* g, void* l) {
    __builtin_amdgcn_global_load_lds(
        (const __attribute__((address_space(1))) unsigned int*)g,
        (__attribute__((address_space(3))) unsigned int*)l,
        16, 0, 0);
}

// ---------- kernel 1: x (fp32, NCHW) -> x_t (bf16, [b][y][x][c]) + pooled atomics ----------
__global__ __launch_bounds__(256) void k_transpose_pool(
        const float* __restrict__ x, short* __restrict__ xt, float* __restrict__ pooled) {
    int y = blockIdx.x;   // 0..63
    int b = blockIdx.y;   // 0..15
    int t = threadIdx.x;  // 0..255
    int si = y >> 4;
    __shared__ float tile[64 * 65];

    for (int cc = 0; cc < 4; ++cc) {
        int cbase = cc * 64;
        for (int q = 0; q < 16; ++q) {
            int c_l = q * 4 + (t >> 6);
            int xx  = t & 63;
            tile[c_l * 65 + xx] =
                x[(((size_t)b * C_ + cbase + c_l) * H_ + y) * W_ + xx];
        }
        __syncthreads();
        {   // pooling: sum 16 x of this row, atomic into pooled[b][si][sj][c]
            int c_l = t & 63, sj = t >> 6;
            float s = 0.f;
            #pragma unroll
            for (int u = 0; u < 16; ++u) s += tile[c_l * 65 + sj * 16 + u];
            atomicAdd(&pooled[((b * 4 + si) * 4 + sj) * 256 + cbase + c_l], s);
        }
        for (int q = 0; q < 16; ++q) {
            int c_l = t & 63;
            int xx  = q * 4 + (t >> 6);
            xt[(((size_t)b * H_ + y) * W_ + xx) * C_ + cbase + c_l] =
                f2bf(tile[c_l * 65 + xx]);
        }
        __syncthreads();
    }
}

// ---------- kernel 2: routing head -> r[b][k][c] ----------
__global__ __launch_bounds__(256) void k_route(
        const float* __restrict__ pooled, const float* __restrict__ rconv_w,
        const float* __restrict__ rconv_b, const float* __restrict__ fc_w,
        const float* __restrict__ fc_b, float* __restrict__ r_buf) {
    int b = blockIdx.x;
    int t = threadIdx.x;
    __shared__ float pl[16][257];   // [ss][c], padded
    __shared__ float y1[256];       // [rcc*16 + ss]

    #pragma unroll
    for (int q = 0; q < 16; ++q)
        pl[q][t] = pooled[b * 4096 + q * 256 + t] * (1.0f / 256.0f);
    __syncthreads();
    {
        int rcc = t >> 4, ss = t & 15;
        float acc = rconv_b[rcc];
        #pragma unroll 8
        for (int c = 0; c < 256; ++c)
            acc += pl[ss][c] * rconv_w[rcc * 256 + c];
        y1[rcc * 16 + ss] = fmaxf(acc, 0.f);
    }
    __syncthreads();
    for (int e0 = 0; e0 < 768; e0 += 256) {
        int e = e0 + t;
        float acc = fc_b[e];
        #pragma unroll 8
        for (int q = 0; q < 256; ++q)
            acc += y1[q] * fc_w[(size_t)e * 256 + q];
        acc = fmaxf(acc, 0.f);
        r_buf[(size_t)b * 768 + e] = 1.f / (1.f + __expf(-acc));
    }
}

// ---------- kernel 3: combine experts -> wcomb[b][o][tap][c] (bf16) ----------
// One block per o; stage E[k][o][c][tap] (contiguous 2304 f32 per expert) in LDS once.
__global__ __launch_bounds__(256) void k_combine(
        const float* __restrict__ E, const float* __restrict__ r_buf,
        short* __restrict__ wcomb) {
    int o = blockIdx.x;   // 0..255
    int t = threadIdx.x;
    __shared__ float eT[3][2304];
    #pragma unroll
    for (int k = 0; k < 3; ++k)
        #pragma unroll
        for (int q = 0; q < 9; ++q)
            eT[k][q * 256 + t] = E[((size_t)k * OC_ + o) * 2304 + q * 256 + t];
    __syncthreads();
    int c = t;
    for (int b = 0; b < 16; ++b) {
        float r0 = r_buf[(size_t)b * 768 + c];
        float r1 = r_buf[(size_t)b * 768 + 256 + c];
        float r2 = r_buf[(size_t)b * 768 + 512 + c];
        short* wo = wcomb + ((size_t)(b * OC_ + o) * 9) * C_;
        #pragma unroll
        for (int tap = 0; tap < 9; ++tap) {
            float v = r0 * eT[0][c * 9 + tap] + r1 * eT[1][c * 9 + tap]
                    + r2 * eT[2][c * 9 + tap];
            wo[tap * C_ + c] = f2bf(v);
        }
    }
}

// ---------- kernel 4: implicit-GEMM conv, M=128 o x N=128 positions, BK=64 ----------
// Grid 1024 (1D, XCD-swizzled). K = tap-major (9) x 4 chunks of 64 ch.
// LDS 16B-slot XOR swizzle by (row&7) -> conflict-free ds_read_b128.
__global__ __launch_bounds__(256) void k_conv(
        const short* __restrict__ xt, const short* __restrict__ wcomb,
        float* __restrict__ out, const short* __restrict__ zbuf) {
    int lin  = blockIdx.x;
    int work = (lin & 7) * 128 + (lin >> 3);   // XCD-contiguous work ranges
    int b      = work >> 6;
    int o_base = ((work >> 5) & 1) * 128;
    int y0     = (work & 31) * 2;

    int t = threadIdx.x;
    int lane = t & 63, w = t >> 6;
    int quad = lane >> 4, l15 = lane & 15;

    __shared__ __align__(16) short aT[128 * 64];  // [o_l][slot] 16 KB
    __shared__ __align__(16) short bT[128 * 64];  // [p_l][slot] 16 KB

    // staging geometry: round r: group g = r*256 + t; row = g>>3; ch8 = g&7
    // source column group cs = ch8 ^ (row & 7)  (XOR swizzle, dest stays lane-ordered)
    const short* aBase[4];
    int bRow[4], bXX[4], bCS[4];
    #pragma unroll
    for (int r = 0; r < 4; ++r) {
        int g = r * 256 + t;
        int row = g >> 3, ch8 = g & 7;
        int cs = ch8 ^ (row & 7);
        aBase[r] = wcomb + ((size_t)(b * OC_ + o_base + row)) * 9 * C_ + cs * 8;
        bRow[r] = row >> 6; bXX[r] = row & 63; bCS[r] = cs;
    }

    f32x4 acc[4][4];
    #pragma unroll
    for (int i = 0; i < 4; ++i)
        #pragma unroll
        for (int j = 0; j < 4; ++j) acc[i][j] = {0.f, 0.f, 0.f, 0.f};

    int m_base = (w & 1) * 64;
    int n_base = (w >> 1) * 64;

    for (int tap = 0; tap < 9; ++tap) {
        int ti = tap / 3, tj = tap % 3;
        const short* bBase[4];
        #pragma unroll
        for (int r = 0; r < 4; ++r) {
            int yy = y0 + bRow[r] + ti - 1;
            int xc = bXX[r] + tj - 1;
            bool valid = ((unsigned)yy < (unsigned)H_) && ((unsigned)xc < (unsigned)W_);
            bBase[r] = valid
                ? xt + ((size_t)(b * H_ + yy) * W_ + xc) * C_ + bCS[r] * 8
                : zbuf;
        }
        #pragma unroll
        for (int cc = 0; cc < 4; ++cc) {
            int kc = tap * 4 + cc;   // A offset: contiguous tap-major K
            __syncthreads();
            #pragma unroll
            for (int r = 0; r < 4; ++r)
                gll16(aBase[r] + kc * 64, &aT[((r << 8) + (w << 6)) * 8]);
            #pragma unroll
            for (int r = 0; r < 4; ++r)
                gll16(bBase[r] + cc * 64, &bT[((r << 8) + (w << 6)) * 8]);
            __syncthreads();

            #pragma unroll
            for (int s = 0; s < 2; ++s) {
                int slot = ((s * 4 + quad) ^ (l15 & 7)) * 8;
                bf16x8 af[4], bfv[4];
                #pragma unroll
                for (int mb = 0; mb < 4; ++mb)
                    af[mb] = *(const bf16x8*)&aT[(m_base + mb * 16 + l15) * 64 + slot];
                #pragma unroll
                for (int nb = 0; nb < 4; ++nb)
                    bfv[nb] = *(const bf16x8*)&bT[(n_base + nb * 16 + l15) * 64 + slot];
                #pragma unroll
                for (int mb = 0; mb < 4; ++mb)
                    #pragma unroll
                    for (int nb = 0; nb < 4; ++nb)
                        acc[mb][nb] = __builtin_amdgcn_mfma_f32_16x16x32_bf16(
                            af[mb], bfv[nb], acc[mb][nb], 0, 0, 0);
            }
        }
    }

    #pragma unroll
    for (int mb = 0; mb < 4; ++mb) {
        #pragma unroll
        for (int nb = 0; nb < 4; ++nb) {
            int p  = n_base + nb * 16 + l15;
            int yy = y0 + (p >> 6);
            int xx = p & 63;
            #pragma unroll
            for (int rg = 0; rg < 4; ++rg) {
                int o = o_base + m_base + mb * 16 + quad * 4 + rg;
                out[(((size_t)b * OC_ + o) * H_ + yy) * W_ + xx] = acc[mb][nb][rg];
            }
        }
    }
}

// ---------- launcher ----------
extern "C" void kernel_launch(void* const* d_in, const int* in_sizes, int n_in,
                              void* d_out, int out_size, void* d_ws, size_t ws_size,
                              hipStream_t stream) {
    const float* x       = (const float*)d_in[0];
    const float* E       = (const float*)d_in[1];
    const float* rconv_w = (const float*)d_in[2];
    const float* rconv_b = (const float*)d_in[3];
    const float* fc_w    = (const float*)d_in[4];
    const float* fc_b    = (const float*)d_in[5];
    float* out = (float*)d_out;

    char* ws = (char*)d_ws;
    short* xt     = (short*)(ws);                    // 32 MiB
    short* wcomb  = (short*)(ws + 33554432);         // 18 MiB -> ends 52428800
    float* pooled = (float*)(ws + 52428800);         // 256 KiB
    float* rbuf   = (float*)(ws + 52690944);         // 48 KiB
    short* zbuf   = (short*)(ws + 52740096);         // 1 KiB zeros

    hipMemsetAsync(zbuf, 0, 1024, stream);
    hipMemsetAsync(pooled, 0, 262144, stream);

    k_transpose_pool<<<dim3(64, 16), 256, 0, stream>>>(x, xt, pooled);
    k_route<<<dim3(16), 256, 0, stream>>>(pooled, rconv_w, rconv_b, fc_w, fc_b, rbuf);
    k_combine<<<dim3(256), 256, 0, stream>>>(E, rbuf, wcomb);
    k_conv<<<dim3(1024), 256, 0, stream>>>(xt, wcomb, out, zbuf);
}

// Round 3
// 243.886 us; speedup vs baseline: 1.2880x; 1.0735x over previous
//
#include <hip/hip_runtime.h>

// ---------- constants ----------
#define B_   16
#define C_   256
#define OC_  256
#define H_   64
#define W_   64

typedef __attribute__((ext_vector_type(8))) __bf16 bf16x8;
typedef __attribute__((ext_vector_type(4))) float  f32x4;

__device__ __forceinline__ short f2bf(float f) {
    unsigned u = __float_as_uint(f);
    u += 0x7fffu + ((u >> 16) & 1u);
    return (short)(u >> 16);
}
__device__ __forceinline__ unsigned pk2(float a, float b) {
    return (unsigned(f2bf(a)) & 0xffffu) | (unsigned(f2bf(b)) << 16);
}
__device__ __forceinline__ void gll16(const void* g, void* l) {
    __builtin_amdgcn_global_load_lds(
        (const __attribute__((address_space(1))) unsigned int*)g,
        (__attribute__((address_space(3))) unsigned int*)l,
        16, 0, 0);
}

// ---------- kernel 1: x (fp32, NCHW) -> x_t (bf16, [b][y][x][c]) + pooled atomics ----------
// float4 loads, 16B packed stores, register+shuffle pooling.
__global__ __launch_bounds__(256) void k_transpose_pool(
        const float* __restrict__ x, short* __restrict__ xt, float* __restrict__ pooled) {
    int y = blockIdx.x, b = blockIdx.y, t = threadIdx.x;
    int si = y >> 4;
    int lane = t & 63, wv = t >> 6;
    int xq = lane & 15, cw = lane >> 4;
    __shared__ float tile[64 * 67];   // stride 67: both phases ~2-way (free)

    for (int cc = 0; cc < 4; ++cc) {
        int cbase = cc * 64;
        if (cc) __syncthreads();
        #pragma unroll
        for (int r = 0; r < 4; ++r) {
            int c_l = r * 16 + wv * 4 + cw;
            float4 v = *(const float4*)&x[(((size_t)b * C_ + cbase + c_l) * H_ + y) * W_ + xq * 4];
            float* tp = &tile[c_l * 67 + xq * 4];
            tp[0] = v.x; tp[1] = v.y; tp[2] = v.z; tp[3] = v.w;
            float s = v.x + v.y + v.z + v.w;       // pooling partial (4 x)
            s += __shfl_xor(s, 1);
            s += __shfl_xor(s, 2);
            if ((lane & 3) == 0)
                atomicAdd(&pooled[((b * 4 + si) * 4 + (xq >> 2)) * 256 + cbase + c_l], s);
        }
        __syncthreads();
        #pragma unroll
        for (int r2 = 0; r2 < 2; ++r2) {
            int u = r2 * 256 + t;
            int xx = u >> 3, cgl = u & 7;
            float f[8];
            #pragma unroll
            for (int j = 0; j < 8; ++j) f[j] = tile[(cgl * 8 + j) * 67 + xx];
            uint4 pkv;
            pkv.x = pk2(f[0], f[1]); pkv.y = pk2(f[2], f[3]);
            pkv.z = pk2(f[4], f[5]); pkv.w = pk2(f[6], f[7]);
            *(uint4*)&xt[(((size_t)b * H_ + y) * W_ + xx) * C_ + cbase + cgl * 8] = pkv;
        }
    }
}

// ---------- kernel 2: routing head -> r[b][k][c] ----------
__global__ __launch_bounds__(256) void k_route(
        const float* __restrict__ pooled, const float* __restrict__ rconv_w,
        const float* __restrict__ rconv_b, const float* __restrict__ fc_w,
        const float* __restrict__ fc_b, float* __restrict__ r_buf) {
    int b = blockIdx.x;
    int t = threadIdx.x;
    __shared__ float pl[16][257];
    __shared__ float y1[256];

    #pragma unroll
    for (int q = 0; q < 16; ++q)
        pl[q][t] = pooled[b * 4096 + q * 256 + t] * (1.0f / 256.0f);
    __syncthreads();
    {
        int rcc = t >> 4, ss = t & 15;
        float acc = rconv_b[rcc];
        #pragma unroll 8
        for (int c = 0; c < 256; ++c)
            acc += pl[ss][c] * rconv_w[rcc * 256 + c];
        y1[rcc * 16 + ss] = fmaxf(acc, 0.f);
    }
    __syncthreads();
    for (int e0 = 0; e0 < 768; e0 += 256) {
        int e = e0 + t;
        float acc = fc_b[e];
        #pragma unroll 8
        for (int q = 0; q < 256; ++q)
            acc += y1[q] * fc_w[(size_t)e * 256 + q];
        acc = fmaxf(acc, 0.f);
        r_buf[(size_t)b * 768 + e] = 1.f / (1.f + __expf(-acc));
    }
}

// ---------- kernel 3: combine experts -> wcomb[b][o][tap][c] (bf16) ----------
__global__ __launch_bounds__(256) void k_combine(
        const float* __restrict__ E, const float* __restrict__ r_buf,
        short* __restrict__ wcomb) {
    int o = blockIdx.x;        // 0..255
    int b0 = blockIdx.y * 4;   // 4 b's per block
    int t = threadIdx.x;
    __shared__ float eT[3][2304];
    #pragma unroll
    for (int k = 0; k < 3; ++k)
        #pragma unroll
        for (int q = 0; q < 9; ++q)
            eT[k][q * 256 + t] = E[((size_t)k * OC_ + o) * 2304 + q * 256 + t];
    __syncthreads();
    int c = t;
    #pragma unroll
    for (int bb = 0; bb < 4; ++bb) {
        int b = b0 + bb;
        float r0 = r_buf[(size_t)b * 768 + c];
        float r1 = r_buf[(size_t)b * 768 + 256 + c];
        float r2 = r_buf[(size_t)b * 768 + 512 + c];
        short* wo = wcomb + ((size_t)(b * OC_ + o) * 9) * C_;
        #pragma unroll
        for (int tap = 0; tap < 9; ++tap) {
            float v = r0 * eT[0][c * 9 + tap] + r1 * eT[1][c * 9 + tap]
                    + r2 * eT[2][c * 9 + tap];
            wo[tap * C_ + c] = f2bf(v);
        }
    }
}

// ---------- kernel 4: implicit-GEMM conv with resident x-window + A double-buffer ----------
// M=128 o, N=128 pos (2 rows), per cc-chunk (64 ch): stage window once,
// loop 9 taps with A prefetched into the other buffer (overlap w/ MFMA).
// LDS = 32KB window + 2x16KB A = 65536 B exactly -> 2 blocks/CU.
__global__ __launch_bounds__(256, 2) void k_conv(
        const short* __restrict__ xt, const short* __restrict__ wcomb,
        float* __restrict__ out, const short* __restrict__ zbuf) {
    int lin  = blockIdx.x;
    int work = (lin & 7) * 128 + (lin >> 3);   // XCD-contiguous: 2 samples/XCD
    int b      = work >> 6;
    int o_base = ((work >> 5) & 1) * 128;
    int y0     = (work & 31) * 2;

    int t = threadIdx.x;
    int lane = t & 63, w = t >> 6;
    int quad = lane >> 4, l15 = lane & 15;

    __shared__ __align__(16) short win[4 * 64 * 64];      // [wrow][xc][slot8][8ch] 32 KB
    __shared__ __align__(16) short abuf[2][128 * 64];     // [o_l][slot8][8ch] 2x16 KB

    // window staging sources (8 rounds x 256 threads = 2048 tasks, halo rows -> zbuf)
    const short* wsrc[8];
    #pragma unroll
    for (int r = 0; r < 8; ++r) {
        int u = r * 256 + t;
        int pos = u >> 3, sp = u & 7;
        int wrow = pos >> 6, xc = pos & 63;
        int yy = y0 - 1 + wrow;
        int ss = sp ^ (xc & 7);                 // XOR swizzle at source
        wsrc[r] = ((unsigned)yy < 64u)
            ? xt + (((size_t)b * 64 + yy) * 64 + xc) * 256 + ss * 8
            : zbuf;
    }
    // A staging sources (4 rounds)
    const short* asrc[4];
    #pragma unroll
    for (int r = 0; r < 4; ++r) {
        int u = r * 256 + t;
        int o_l = u >> 3, sp = u & 7;
        int ss = sp ^ (o_l & 7);
        asrc[r] = wcomb + (((size_t)b * 256 + o_base + o_l) * 9) * 256 + ss * 8;
    }

    int m_base = (w & 1) * 64;
    int n_base = (w >> 1) * 64;
    int ry0 = n_base >> 6;                       // output row within pair (0/1)
    int xb[4];
    #pragma unroll
    for (int nb = 0; nb < 4; ++nb) xb[nb] = nb * 16 + l15;   // x coord (wave-invariant)

    f32x4 acc[4][4];
    #pragma unroll
    for (int i = 0; i < 4; ++i)
        #pragma unroll
        for (int j = 0; j < 4; ++j) acc[i][j] = {0.f, 0.f, 0.f, 0.f};

    for (int cc = 0; cc < 4; ++cc) {
        int ccOff = cc * 64;
        // stage window + A[tap0] (prev-iteration tail barrier protects reuse)
        #pragma unroll
        for (int r = 0; r < 8; ++r)
            gll16(wsrc[r] + ccOff, &win[(r * 256 + w * 64) * 8]);
        #pragma unroll
        for (int r = 0; r < 4; ++r)
            gll16(asrc[r] + ccOff, &abuf[0][(r * 256 + w * 64) * 8]);
        __syncthreads();

        #pragma unroll
        for (int tap = 0; tap < 9; ++tap) {
            const int ti = tap / 3, tj = tap % 3;
            const int cur = tap & 1;
            if (tap < 8) {   // prefetch next tap's A into the other buffer
                int off2 = (tap + 1) * 256 + ccOff;
                #pragma unroll
                for (int r = 0; r < 4; ++r)
                    gll16(asrc[r] + off2, &abuf[cur ^ 1][(r * 256 + w * 64) * 8]);
            }
            int wrb = (ry0 + ti) * 4096;         // window row base (shorts)
            #pragma unroll
            for (int s = 0; s < 2; ++s) {
                int slog = s * 4 + quad;
                bf16x8 af[4], bv[4];
                #pragma unroll
                for (int mb = 0; mb < 4; ++mb) {
                    int o_l = m_base + mb * 16 + l15;
                    af[mb] = *(const bf16x8*)&abuf[cur][o_l * 64 + ((slog ^ (o_l & 7)) * 8)];
                }
                #pragma unroll
                for (int nb = 0; nb < 4; ++nb) {
                    int xc = xb[nb] + (tj - 1);
                    bool ok = ((unsigned)xc < 64u);
                    int xs = ok ? xc : 0;
                    bf16x8 v = *(const bf16x8*)&win[wrb + xs * 64 + ((slog ^ (xs & 7)) * 8)];
                    bf16x8 zz = {};
                    bv[nb] = ok ? v : zz;        // column halo is zero
                }
                #pragma unroll
                for (int mb = 0; mb < 4; ++mb)
                    #pragma unroll
                    for (int nb = 0; nb < 4; ++nb)
                        acc[mb][nb] = __builtin_amdgcn_mfma_f32_16x16x32_bf16(
                            af[mb], bv[nb], acc[mb][nb], 0, 0, 0);
            }
            __syncthreads();   // drains prefetch vmcnt + protects buffer swap
        }
    }

    #pragma unroll
    for (int mb = 0; mb < 4; ++mb) {
        #pragma unroll
        for (int nb = 0; nb < 4; ++nb) {
            int p  = n_base + nb * 16 + l15;
            int yy = y0 + (p >> 6);
            int xx = p & 63;
            #pragma unroll
            for (int rg = 0; rg < 4; ++rg) {
                int o = o_base + m_base + mb * 16 + quad * 4 + rg;
                out[(((size_t)b * OC_ + o) * H_ + yy) * W_ + xx] = acc[mb][nb][rg];
            }
        }
    }
}

// ---------- launcher ----------
extern "C" void kernel_launch(void* const* d_in, const int* in_sizes, int n_in,
                              void* d_out, int out_size, void* d_ws, size_t ws_size,
                              hipStream_t stream) {
    const float* x       = (const float*)d_in[0];
    const float* E       = (const float*)d_in[1];
    const float* rconv_w = (const float*)d_in[2];
    const float* rconv_b = (const float*)d_in[3];
    const float* fc_w    = (const float*)d_in[4];
    const float* fc_b    = (const float*)d_in[5];
    float* out = (float*)d_out;

    char* ws = (char*)d_ws;
    short* xt     = (short*)(ws);                    // 32 MiB
    short* wcomb  = (short*)(ws + 33554432);         // 18 MiB
    float* pooled = (float*)(ws + 52428800);         // 256 KiB
    short* zbuf   = (short*)(ws + 52690944);         // 1 KiB zeros (adjacent to pooled)
    float* rbuf   = (float*)(ws + 52692992);         // 48 KiB

    hipMemsetAsync(pooled, 0, 262144 + 1024, stream);   // pooled + zbuf in one node

    k_transpose_pool<<<dim3(64, 16), 256, 0, stream>>>(x, xt, pooled);
    k_route<<<dim3(16), 256, 0, stream>>>(pooled, rconv_w, rconv_b, fc_w, fc_b, rbuf);
    k_combine<<<dim3(256, 4), 256, 0, stream>>>(E, rbuf, wcomb);
    k_conv<<<dim3(1024), 256, 0, stream>>>(xt, wcomb, out, zbuf);
}